// Round 5
// baseline (1451.924 us; speedup 1.0000x reference)
//
#include <hip/hip_runtime.h>

#define Bv 2
#define Nv 2048
#define Cv 512
#define Hv 8
#define Dv 64
#define CAP 256   // candidate cap per row (expected ~45 with online threshold)

typedef __attribute__((ext_vector_type(8))) short s16x8;
typedef __attribute__((ext_vector_type(4))) float f32x4;

__device__ __forceinline__ unsigned short f2bf(float f) {
  union { float f; unsigned u; } x; x.f = f;
  return (unsigned short)((x.u + 0x7fffu + ((x.u >> 16) & 1u)) >> 16);
}
__device__ __forceinline__ float bf2f(unsigned short u) {
  union { unsigned u; float f; } x; x.u = ((unsigned)u) << 16;
  return x.f;
}
// order-preserving float -> uint key (uint compare == float compare)
__device__ __forceinline__ unsigned fkey(float f) {
  unsigned u = __float_as_uint(f);
  return (u & 0x80000000u) ? ~u : (u | 0x80000000u);
}
__device__ __forceinline__ float funkey(unsigned k) {
  unsigned u = (k & 0x80000000u) ? (k ^ 0x80000000u) : ~k;
  return __uint_as_float(u);
}

// ---------------------------------------------------------------------------
// K0: convert x, Wq, Wk, Wv, Wo to bf16 (blockIdx.y selects tensor)
// ---------------------------------------------------------------------------
__global__ __launch_bounds__(256) void cvt5(
    const float* __restrict__ x, const float* __restrict__ wq,
    const float* __restrict__ wk, const float* __restrict__ wv_,
    const float* __restrict__ wo,
    unsigned short* __restrict__ xb, unsigned short* __restrict__ wqb,
    unsigned short* __restrict__ wkb, unsigned short* __restrict__ wvb,
    unsigned short* __restrict__ wob) {
  const float* s; unsigned short* d; int n;
  switch (blockIdx.y) {
    case 0: s = x;   d = xb;  n = Bv * Nv * Cv; break;
    case 1: s = wq;  d = wqb; n = Cv * Cv; break;
    case 2: s = wk;  d = wkb; n = Cv * Cv; break;
    case 3: s = wv_; d = wvb; n = Cv * Cv; break;
    default: s = wo; d = wob; n = Cv * Cv; break;
  }
  int i = (blockIdx.x * 256 + threadIdx.x) * 4;
  if (i < n) {
    float4 v = *(const float4*)(s + i);
    ushort4 o;
    o.x = f2bf(v.x); o.y = f2bf(v.y); o.z = f2bf(v.z); o.w = f2bf(v.w);
    *(ushort4*)(d + i) = o;
  }
}

// ---------------------------------------------------------------------------
// K1: Q/K/V = x @ W^T + b, all bf16 in, bf16 out [B,H,N,D]
// ---------------------------------------------------------------------------
__global__ __launch_bounds__(256) void proj_qkv(
    const unsigned short* __restrict__ xb,
    const unsigned short* __restrict__ wqb, const float* __restrict__ bq,
    const unsigned short* __restrict__ wkb, const float* __restrict__ bk,
    const unsigned short* __restrict__ wvb, const float* __restrict__ bv,
    unsigned short* __restrict__ Qbf, unsigned short* __restrict__ Kbf,
    unsigned short* __restrict__ Vbf) {
  const int lane = threadIdx.x & 63;
  const int wv   = threadIdx.x >> 6;
  const int l16  = lane & 15, quad = lane >> 4;
  const int mbase = blockIdx.x * 64 + wv * 16;
  const int nbase = blockIdx.y * 64;
  const int mat   = blockIdx.z;
  const unsigned short* W = (mat == 0) ? wqb : (mat == 1) ? wkb : wvb;
  const float* bias = (mat == 0) ? bq : (mat == 1) ? bk : bv;
  unsigned short* dst = (mat == 0) ? Qbf : (mat == 1) ? Kbf : Vbf;

  f32x4 acc[4] = {};
  for (int kk = 0; kk < Cv; kk += 32) {
    s16x8 a = *(const s16x8*)(xb + (size_t)(mbase + l16) * Cv + kk + quad * 8);
#pragma unroll
    for (int ct = 0; ct < 4; ct++) {
      s16x8 bfr = *(const s16x8*)(W + (size_t)(nbase + ct * 16 + l16) * Cv + kk + quad * 8);
      acc[ct] = __builtin_amdgcn_mfma_f32_16x16x32_bf16(a, bfr, acc[ct], 0, 0, 0);
    }
  }
#pragma unroll
  for (int ct = 0; ct < 4; ct++) {
    int n = nbase + ct * 16 + l16;
    int h = n >> 6, d = n & 63;
    float bb = bias[n];
#pragma unroll
    for (int r = 0; r < 4; r++) {
      int m = mbase + quad * 4 + r;  // C/D: row=quad*4+reg, col=lane&15
      int bidx = m >> 11, nn = m & 2047;
      dst[(((size_t)bidx * Hv + h) * Nv + nn) * Dv + d] = f2bf(acc[ct][r] + bb);
    }
  }
}

// ---------------------------------------------------------------------------
// K2: sparse fused attention, SINGLE QK^T pass.
// Online LDS atomicMax threshold: append candidate iff fkey(val+1) > rowkey
// (i.e. val > curmax-1). Stale reads only over-collect (p=0 entries) — never
// lose support. Then bisection for tau, compact (idx,p) lists -> global ws,
// sparse PV. Dense attn rows written by attn_write kernel.
// ---------------------------------------------------------------------------
__global__ __launch_bounds__(256) void attn_sparse(
    const unsigned short* __restrict__ Qbf, const unsigned short* __restrict__ Kbf,
    const unsigned short* __restrict__ Vbf, float* __restrict__ attn_out,
    unsigned short* __restrict__ Obf,
    float* __restrict__ candp_g, unsigned short* __restrict__ candi_g,
    int* __restrict__ cnt_g) {
  __shared__ unsigned rowkey[16];
  __shared__ float candv[16][CAP];
  __shared__ unsigned short candi[16][CAP];
  __shared__ int   cnt[16];
  __shared__ float lo_s[16], hi_s[16], sum_s[16], taud[16];
  __shared__ int   oflow;

  const int lane = threadIdx.x & 63;
  const int wv   = threadIdx.x >> 6;
  const int l16  = lane & 15, quad = lane >> 4;
  const int bh    = blockIdx.x >> 7;
  const int qbase = (blockIdx.x & 127) << 4;
  const int b = bh >> 3, h = bh & 7;

  const unsigned short* Qh = Qbf + (size_t)bh * Nv * Dv;
  const unsigned short* Kh = Kbf + (size_t)bh * Nv * Dv;
  const unsigned short* Vh = Vbf + (size_t)bh * Nv * Dv;
  float* attn_bh = attn_out + (size_t)bh * Nv * Nv;

  if (threadIdx.x < 16) {
    cnt[threadIdx.x] = 0;
    rowkey[threadIdx.x] = fkey(-1e30f);
  }
  if (threadIdx.x == 0) oflow = 0;
  __syncthreads();

  s16x8 a0 = *(const s16x8*)(Qh + (size_t)(qbase + l16) * Dv + quad * 8);
  s16x8 a1 = *(const s16x8*)(Qh + (size_t)(qbase + l16) * Dv + 32 + quad * 8);

  // ---- single pass: scores + online threshold + candidate collection ----
  for (int t = 0; t < 32; t++) {
    int col0 = (t * 4 + wv) * 16;
    s16x8 b0 = *(const s16x8*)(Kh + (size_t)(col0 + l16) * Dv + quad * 8);
    s16x8 b1 = *(const s16x8*)(Kh + (size_t)(col0 + l16) * Dv + 32 + quad * 8);
    f32x4 c = {};
    c = __builtin_amdgcn_mfma_f32_16x16x32_bf16(a0, b0, c, 0, 0, 0);
    c = __builtin_amdgcn_mfma_f32_16x16x32_bf16(a1, b1, c, 0, 0, 0);
#pragma unroll
    for (int r = 0; r < 4; r++) {
      float val = c[r] * 0.125f;
      int row = quad * 4 + r;
      unsigned cur = rowkey[row];                 // LDS broadcast read
      if (fkey(val + 1.0f) > cur) {               // val > curmax - 1
        int pos = atomicAdd(&cnt[row], 1);
        if (pos < CAP) {
          candv[row][pos] = val;
          candi[row][pos] = (unsigned short)(col0 + l16);
        }
        unsigned k = fkey(val);
        if (k > cur) atomicMax(&rowkey[row], k);
      }
    }
  }
  __syncthreads();
  if (threadIdx.x < 16 && cnt[threadIdx.x] > CAP) oflow = 1;
  __syncthreads();

  if (oflow == 0) {
    // ---- bisection; wave wv owns rows wv*4..wv*4+3 ----
    float cv[4][4], lo[4], hi[4], tau[4];
#pragma unroll
    for (int i = 0; i < 4; i++) {
      int row = wv * 4 + i;
      int c_ = cnt[row];
#pragma unroll
      for (int j = 0; j < 4; j++) {
        int p = lane + j * 64;
        cv[i][j] = (p < c_) ? candv[row][p] : -1e30f;
      }
      float mx = funkey(rowkey[row]);
      lo[i] = mx - 1.0f; hi[i] = mx;
    }
    for (int it = 0; it < 22; it++) {
      float mid[4], s[4];
#pragma unroll
      for (int i = 0; i < 4; i++) {
        mid[i] = 0.5f * (lo[i] + hi[i]);
        float ss = 0.0f;
#pragma unroll
        for (int j = 0; j < 4; j++) ss += fmaxf(cv[i][j] - mid[i], 0.0f);
        s[i] = ss;
      }
#pragma unroll
      for (int off = 32; off > 0; off >>= 1)
#pragma unroll
        for (int i = 0; i < 4; i++) s[i] += __shfl_xor(s[i], off, 64);
#pragma unroll
      for (int i = 0; i < 4; i++) {
        if (s[i] > 1.0f) lo[i] = mid[i]; else hi[i] = mid[i];
      }
    }
#pragma unroll
    for (int i = 0; i < 4; i++) tau[i] = 0.5f * (lo[i] + hi[i]);

    // ---- write compact (idx, p) lists for attn_write ----
#pragma unroll
    for (int i = 0; i < 4; i++) {
      int row = wv * 4 + i;
      size_t rowg = (size_t)blockIdx.x * 16 + row;
      int c_ = cnt[row];
      for (int jj = lane; jj < c_; jj += 64) {
        candp_g[rowg * CAP + jj] = fmaxf(candv[row][jj] - tau[i], 0.0f);
        candi_g[rowg * CAP + jj] = candi[row][jj];
      }
      if (lane == 0) cnt_g[rowg] = c_;
    }

    // ---- sparse PV (fp32 VALU); lane = output dim ----
    float o[4] = {0, 0, 0, 0};
#pragma unroll
    for (int i = 0; i < 4; i++) {
      int row = wv * 4 + i;
      int c_ = cnt[row];
      for (int jj = 0; jj < c_; jj++) {
        float p = fmaxf(candv[row][jj] - tau[i], 0.0f);
        o[i] += p * bf2f(Vh[(size_t)candi[row][jj] * Dv + lane]);
      }
    }
#pragma unroll
    for (int i = 0; i < 4; i++) {
      int row = wv * 4 + i;
      Obf[((size_t)(b * Nv + qbase + row)) * Cv + h * Dv + lane] = f2bf(o[i]);
    }
  } else {
    // ---- pathological fallback: dense bisection via recompute; writes attn
    //      rows densely itself and flags cnt_g = -1 so attn_write skips ----
    if (threadIdx.x < 16) {
      float mx = funkey(rowkey[threadIdx.x]);
      lo_s[threadIdx.x] = mx - 1.0f; hi_s[threadIdx.x] = mx;
      cnt_g[(size_t)blockIdx.x * 16 + threadIdx.x] = -1;
    }
    __syncthreads();
    for (int it = 0; it < 26; it++) {
      if (threadIdx.x < 16) sum_s[threadIdx.x] = 0.0f;
      __syncthreads();
      float part[4] = {0, 0, 0, 0};
      for (int t = 0; t < 32; t++) {
        int col0 = (t * 4 + wv) * 16;
        s16x8 b0 = *(const s16x8*)(Kh + (size_t)(col0 + l16) * Dv + quad * 8);
        s16x8 b1 = *(const s16x8*)(Kh + (size_t)(col0 + l16) * Dv + 32 + quad * 8);
        f32x4 c = {};
        c = __builtin_amdgcn_mfma_f32_16x16x32_bf16(a0, b0, c, 0, 0, 0);
        c = __builtin_amdgcn_mfma_f32_16x16x32_bf16(a1, b1, c, 0, 0, 0);
#pragma unroll
        for (int r = 0; r < 4; r++) {
          int row = quad * 4 + r;
          float mid = 0.5f * (lo_s[row] + hi_s[row]);
          part[r] += fmaxf(c[r] * 0.125f - mid, 0.0f);
        }
      }
#pragma unroll
      for (int off = 1; off <= 8; off <<= 1)
#pragma unroll
        for (int r = 0; r < 4; r++) part[r] += __shfl_xor(part[r], off, 64);
      if (l16 == 0) {
#pragma unroll
        for (int r = 0; r < 4; r++) atomicAdd(&sum_s[quad * 4 + r], part[r]);
      }
      __syncthreads();
      if (threadIdx.x < 16) {
        float mid = 0.5f * (lo_s[threadIdx.x] + hi_s[threadIdx.x]);
        if (sum_s[threadIdx.x] > 1.0f) lo_s[threadIdx.x] = mid; else hi_s[threadIdx.x] = mid;
      }
      __syncthreads();
    }
    if (threadIdx.x < 16) taud[threadIdx.x] = 0.5f * (lo_s[threadIdx.x] + hi_s[threadIdx.x]);
    __syncthreads();
    // dense attn write by recompute
    for (int t = 0; t < 32; t++) {
      int col0 = (t * 4 + wv) * 16;
      s16x8 b0 = *(const s16x8*)(Kh + (size_t)(col0 + l16) * Dv + quad * 8);
      s16x8 b1 = *(const s16x8*)(Kh + (size_t)(col0 + l16) * Dv + 32 + quad * 8);
      f32x4 c = {};
      c = __builtin_amdgcn_mfma_f32_16x16x32_bf16(a0, b0, c, 0, 0, 0);
      c = __builtin_amdgcn_mfma_f32_16x16x32_bf16(a1, b1, c, 0, 0, 0);
#pragma unroll
      for (int r = 0; r < 4; r++) {
        int row = quad * 4 + r;
        attn_bh[(size_t)(qbase + row) * Nv + col0 + l16] =
            fmaxf(c[r] * 0.125f - taud[row], 0.0f);
      }
    }
    __threadfence();
    __syncthreads();
    // slow, correct PV: read back dense attn rows
    float o[4] = {0, 0, 0, 0};
#pragma unroll
    for (int i = 0; i < 4; i++) {
      int row = wv * 4 + i;
      const float* arow = attn_bh + (size_t)(qbase + row) * Nv;
      for (int k = 0; k < Nv; k++) {
        float p = arow[k];
        if (p > 0.0f) o[i] += p * bf2f(Vh[(size_t)k * Dv + lane]);
      }
    }
#pragma unroll
    for (int i = 0; i < 4; i++) {
      int row = wv * 4 + i;
      Obf[((size_t)(b * Nv + qbase + row)) * Cv + h * Dv + lane] = f2bf(o[i]);
    }
  }
}

// ---------------------------------------------------------------------------
// K2b: dense attn row writer. One 64-thread (single-wave) block per q-row:
// zero 8KB LDS row, scatter <=cnt entries, stream out as float4. Intra-wave
// barriers only -> no multi-wave barrier stalls. Skips fallback rows (cnt<0).
// ---------------------------------------------------------------------------
__global__ __launch_bounds__(64) void attn_write(
    const float* __restrict__ candp_g, const unsigned short* __restrict__ candi_g,
    const int* __restrict__ cnt_g, float* __restrict__ attn_out) {
  __shared__ float dense[Nv];
  const size_t rowg = blockIdx.x;
  const int t = threadIdx.x;
  const int c_ = cnt_g[rowg];
  if (c_ < 0) return;  // fallback row: already written densely

  float4* d4 = (float4*)dense;
  const float4 z4 = make_float4(0.f, 0.f, 0.f, 0.f);
#pragma unroll
  for (int j = 0; j < 8; j++) d4[j * 64 + t] = z4;
  __syncthreads();
  for (int jj = t; jj < c_; jj += 64)
    dense[candi_g[rowg * CAP + jj]] = candp_g[rowg * CAP + jj];
  __syncthreads();
  float* arow = attn_out + rowg * Nv;
#pragma unroll
  for (int j = 0; j < 8; j++)
    *(float4*)(arow + (j * 64 + t) * 4) = d4[j * 64 + t];
}

// ---------------------------------------------------------------------------
// K3: out = O @ Wo^T + bo (bf16 in, fp32 out)
// ---------------------------------------------------------------------------
__global__ __launch_bounds__(256) void proj_out(
    const unsigned short* __restrict__ Obf, const unsigned short* __restrict__ wob,
    const float* __restrict__ bo, float* __restrict__ out) {
  const int lane = threadIdx.x & 63;
  const int wv   = threadIdx.x >> 6;
  const int l16  = lane & 15, quad = lane >> 4;
  const int mbase = blockIdx.x * 64 + wv * 16;
  const int nbase = blockIdx.y * 64;

  f32x4 acc[4] = {};
  for (int kk = 0; kk < Cv; kk += 32) {
    s16x8 a = *(const s16x8*)(Obf + (size_t)(mbase + l16) * Cv + kk + quad * 8);
#pragma unroll
    for (int ct = 0; ct < 4; ct++) {
      s16x8 bfr = *(const s16x8*)(wob + (size_t)(nbase + ct * 16 + l16) * Cv + kk + quad * 8);
      acc[ct] = __builtin_amdgcn_mfma_f32_16x16x32_bf16(a, bfr, acc[ct], 0, 0, 0);
    }
  }
#pragma unroll
  for (int ct = 0; ct < 4; ct++) {
    int n = nbase + ct * 16 + l16;
    float bb = bo[n];
#pragma unroll
    for (int r = 0; r < 4; r++) {
      int m = mbase + quad * 4 + r;
      out[(size_t)m * Cv + n] = acc[ct][r] + bb;
    }
  }
}

extern "C" void kernel_launch(void* const* d_in, const int* in_sizes, int n_in,
                              void* d_out, int out_size, void* d_ws, size_t ws_size,
                              hipStream_t stream) {
  (void)in_sizes; (void)n_in; (void)out_size; (void)ws_size;
  const float* x  = (const float*)d_in[0];
  const float* Wq = (const float*)d_in[1];
  const float* bq = (const float*)d_in[2];
  const float* Wk = (const float*)d_in[3];
  const float* bk = (const float*)d_in[4];
  const float* Wv = (const float*)d_in[5];
  const float* bv = (const float*)d_in[6];
  const float* Wo = (const float*)d_in[7];
  const float* bo = (const float*)d_in[8];

  float* out  = (float*)d_out;                       // [B,N,C]
  float* attn = out + (size_t)Bv * Nv * Cv;          // [B,H,N,N]

  const size_t NROWS = (size_t)Bv * Hv * Nv;         // 32768

  unsigned short* xb  = (unsigned short*)d_ws;
  unsigned short* wqb = xb  + (size_t)Bv * Nv * Cv;
  unsigned short* wkb = wqb + (size_t)Cv * Cv;
  unsigned short* wvb = wkb + (size_t)Cv * Cv;
  unsigned short* wob = wvb + (size_t)Cv * Cv;
  unsigned short* Qbf = wob + (size_t)Cv * Cv;
  unsigned short* Kbf = Qbf + (size_t)Bv * Hv * Nv * Dv;
  unsigned short* Vbf = Kbf + (size_t)Bv * Hv * Nv * Dv;
  unsigned short* end16 = Vbf + (size_t)Bv * Hv * Nv * Dv;
  float*          candp = (float*)end16;             // 32768*CAP f32 = 33.5MB
  unsigned short* candi = (unsigned short*)(candp + NROWS * CAP);  // 16.8MB
  int*            cntg  = (int*)(candi + NROWS * CAP);             // 128KB
  unsigned short* Obf = xb;   // alias: xb dead after proj_qkv

  cvt5<<<dim3((Bv * Nv * Cv) / 4 / 256, 5), 256, 0, stream>>>(
      x, Wq, Wk, Wv, Wo, xb, wqb, wkb, wvb, wob);
  proj_qkv<<<dim3((Bv * Nv) / 64, Cv / 64, 3), 256, 0, stream>>>(
      xb, wqb, bq, wkb, bk, wvb, bv, Qbf, Kbf, Vbf);
  attn_sparse<<<dim3(Bv * Hv * (Nv / 16)), 256, 0, stream>>>(
      Qbf, Kbf, Vbf, attn, Obf, candp, candi, cntg);
  attn_write<<<dim3((unsigned)NROWS), 64, 0, stream>>>(candp, candi, cntg, attn);
  proj_out<<<dim3((Bv * Nv) / 64, Cv / 64), 256, 0, stream>>>(Obf, wob, bo, out);
}

// Round 6
// 1414.548 us; speedup vs baseline: 1.0264x; 1.0264x over previous
//
#include <hip/hip_runtime.h>

#define Bv 2
#define Nv 2048
#define Cv 512
#define Hv 8
#define Dv 64
#define CAP 256   // candidate cap per row (expected ~75 with primed online threshold)

typedef __attribute__((ext_vector_type(8))) short s16x8;
typedef __attribute__((ext_vector_type(4))) float f32x4;

__device__ __forceinline__ unsigned short f2bf(float f) {
  union { float f; unsigned u; } x; x.f = f;
  return (unsigned short)((x.u + 0x7fffu + ((x.u >> 16) & 1u)) >> 16);
}
__device__ __forceinline__ float bf2f(unsigned short u) {
  union { unsigned u; float f; } x; x.u = ((unsigned)u) << 16;
  return x.f;
}
// order-preserving float -> uint key (uint compare == float compare)
__device__ __forceinline__ unsigned fkey(float f) {
  unsigned u = __float_as_uint(f);
  return (u & 0x80000000u) ? ~u : (u | 0x80000000u);
}
__device__ __forceinline__ float funkey(unsigned k) {
  unsigned u = (k & 0x80000000u) ? (k ^ 0x80000000u) : ~k;
  return __uint_as_float(u);
}

// ---------------------------------------------------------------------------
// K0: convert x, Wq, Wk, Wv, Wo to bf16 (blockIdx.y selects tensor)
// ---------------------------------------------------------------------------
__global__ __launch_bounds__(256) void cvt5(
    const float* __restrict__ x, const float* __restrict__ wq,
    const float* __restrict__ wk, const float* __restrict__ wv_,
    const float* __restrict__ wo,
    unsigned short* __restrict__ xb, unsigned short* __restrict__ wqb,
    unsigned short* __restrict__ wkb, unsigned short* __restrict__ wvb,
    unsigned short* __restrict__ wob) {
  const float* s; unsigned short* d; int n;
  switch (blockIdx.y) {
    case 0: s = x;   d = xb;  n = Bv * Nv * Cv; break;
    case 1: s = wq;  d = wqb; n = Cv * Cv; break;
    case 2: s = wk;  d = wkb; n = Cv * Cv; break;
    case 3: s = wv_; d = wvb; n = Cv * Cv; break;
    default: s = wo; d = wob; n = Cv * Cv; break;
  }
  int i = (blockIdx.x * 256 + threadIdx.x) * 4;
  if (i < n) {
    float4 v = *(const float4*)(s + i);
    ushort4 o;
    o.x = f2bf(v.x); o.y = f2bf(v.y); o.z = f2bf(v.z); o.w = f2bf(v.w);
    *(ushort4*)(d + i) = o;
  }
}

// ---------------------------------------------------------------------------
// K1: Q/K/V = x @ W^T + b, all bf16 in, bf16 out [B,H,N,D]
// ---------------------------------------------------------------------------
__global__ __launch_bounds__(256) void proj_qkv(
    const unsigned short* __restrict__ xb,
    const unsigned short* __restrict__ wqb, const float* __restrict__ bq,
    const unsigned short* __restrict__ wkb, const float* __restrict__ bk,
    const unsigned short* __restrict__ wvb, const float* __restrict__ bv,
    unsigned short* __restrict__ Qbf, unsigned short* __restrict__ Kbf,
    unsigned short* __restrict__ Vbf) {
  const int lane = threadIdx.x & 63;
  const int wv   = threadIdx.x >> 6;
  const int l16  = lane & 15, quad = lane >> 4;
  const int mbase = blockIdx.x * 64 + wv * 16;
  const int nbase = blockIdx.y * 64;
  const int mat   = blockIdx.z;
  const unsigned short* W = (mat == 0) ? wqb : (mat == 1) ? wkb : wvb;
  const float* bias = (mat == 0) ? bq : (mat == 1) ? bk : bv;
  unsigned short* dst = (mat == 0) ? Qbf : (mat == 1) ? Kbf : Vbf;

  f32x4 acc[4] = {};
  for (int kk = 0; kk < Cv; kk += 32) {
    s16x8 a = *(const s16x8*)(xb + (size_t)(mbase + l16) * Cv + kk + quad * 8);
#pragma unroll
    for (int ct = 0; ct < 4; ct++) {
      s16x8 bfr = *(const s16x8*)(W + (size_t)(nbase + ct * 16 + l16) * Cv + kk + quad * 8);
      acc[ct] = __builtin_amdgcn_mfma_f32_16x16x32_bf16(a, bfr, acc[ct], 0, 0, 0);
    }
  }
#pragma unroll
  for (int ct = 0; ct < 4; ct++) {
    int n = nbase + ct * 16 + l16;
    int h = n >> 6, d = n & 63;
    float bb = bias[n];
#pragma unroll
    for (int r = 0; r < 4; r++) {
      int m = mbase + quad * 4 + r;  // C/D: row=quad*4+reg, col=lane&15
      int bidx = m >> 11, nn = m & 2047;
      dst[(((size_t)bidx * Hv + h) * Nv + nn) * Dv + d] = f2bf(acc[ct][r] + bb);
    }
  }
}

// ---------------------------------------------------------------------------
// K2: sparse fused attention, single QK^T pass with PRIMED online threshold.
// Prime: tile t=0 -> per-row max -> rowkey, barrier. Collect: append iff
// val > curmax-1 (stale reads only over-collect, never lose support).
// Bisection for tau; ballot-prefix compaction to true support (p>0, ~13);
// compact lists -> global ws (for attn_write); 4-way unrolled sparse PV.
// ---------------------------------------------------------------------------
__global__ __launch_bounds__(256) void attn_sparse(
    const unsigned short* __restrict__ Qbf, const unsigned short* __restrict__ Kbf,
    const unsigned short* __restrict__ Vbf, float* __restrict__ attn_out,
    unsigned short* __restrict__ Obf,
    float* __restrict__ candp_g, unsigned short* __restrict__ candi_g,
    int* __restrict__ cnt_g) {
  __shared__ unsigned rowkey[16];
  __shared__ float candv[16][CAP];
  __shared__ unsigned short candi[16][CAP];
  __shared__ int   cnt[16];
  __shared__ float lo_s[16], hi_s[16], sum_s[16], taud[16];
  __shared__ int   oflow;

  const int lane = threadIdx.x & 63;
  const int wv   = threadIdx.x >> 6;
  const int l16  = lane & 15, quad = lane >> 4;
  const unsigned long long lt_mask = (1ull << lane) - 1ull;
  const int bh    = blockIdx.x >> 7;
  const int qbase = (blockIdx.x & 127) << 4;
  const int b = bh >> 3, h = bh & 7;

  const unsigned short* Qh = Qbf + (size_t)bh * Nv * Dv;
  const unsigned short* Kh = Kbf + (size_t)bh * Nv * Dv;
  const unsigned short* Vh = Vbf + (size_t)bh * Nv * Dv;
  float* attn_bh = attn_out + (size_t)bh * Nv * Nv;

  if (threadIdx.x < 16) {
    cnt[threadIdx.x] = 0;
    rowkey[threadIdx.x] = fkey(-1e30f);
  }
  if (threadIdx.x == 0) oflow = 0;
  __syncthreads();

  s16x8 a0 = *(const s16x8*)(Qh + (size_t)(qbase + l16) * Dv + quad * 8);
  s16x8 a1 = *(const s16x8*)(Qh + (size_t)(qbase + l16) * Dv + 32 + quad * 8);

  // ---- prime: tile t=0 row maxes -> rowkey (kills the t=0 append burst) ----
  {
    int col0 = wv * 16;
    s16x8 b0 = *(const s16x8*)(Kh + (size_t)(col0 + l16) * Dv + quad * 8);
    s16x8 b1 = *(const s16x8*)(Kh + (size_t)(col0 + l16) * Dv + 32 + quad * 8);
    f32x4 c = {};
    c = __builtin_amdgcn_mfma_f32_16x16x32_bf16(a0, b0, c, 0, 0, 0);
    c = __builtin_amdgcn_mfma_f32_16x16x32_bf16(a1, b1, c, 0, 0, 0);
    float rm[4];
#pragma unroll
    for (int r = 0; r < 4; r++) rm[r] = c[r] * 0.125f;
#pragma unroll
    for (int off = 1; off <= 8; off <<= 1)
#pragma unroll
      for (int r = 0; r < 4; r++) rm[r] = fmaxf(rm[r], __shfl_xor(rm[r], off, 64));
    if (l16 == 0) {
#pragma unroll
      for (int r = 0; r < 4; r++) atomicMax(&rowkey[quad * 4 + r], fkey(rm[r]));
    }
  }
  __syncthreads();

  // ---- collection pass (recomputes t=0; 2 extra MFMAs, negligible) ----
  for (int t = 0; t < 32; t++) {
    int col0 = (t * 4 + wv) * 16;
    s16x8 b0 = *(const s16x8*)(Kh + (size_t)(col0 + l16) * Dv + quad * 8);
    s16x8 b1 = *(const s16x8*)(Kh + (size_t)(col0 + l16) * Dv + 32 + quad * 8);
    f32x4 c = {};
    c = __builtin_amdgcn_mfma_f32_16x16x32_bf16(a0, b0, c, 0, 0, 0);
    c = __builtin_amdgcn_mfma_f32_16x16x32_bf16(a1, b1, c, 0, 0, 0);
#pragma unroll
    for (int r = 0; r < 4; r++) {
      float val = c[r] * 0.125f;
      int row = quad * 4 + r;
      unsigned cur = rowkey[row];                 // LDS broadcast read (stale ok)
      if (fkey(val + 1.0f) > cur) {               // val > curmax - 1
        int pos = atomicAdd(&cnt[row], 1);
        if (pos < CAP) {
          candv[row][pos] = val;
          candi[row][pos] = (unsigned short)(col0 + l16);
        }
        unsigned k = fkey(val);
        if (k > cur) atomicMax(&rowkey[row], k);
      }
    }
  }
  __syncthreads();
  if (threadIdx.x < 16 && cnt[threadIdx.x] > CAP) oflow = 1;
  __syncthreads();

  if (oflow == 0) {
    // ---- bisection; wave wv owns rows wv*4..wv*4+3 ----
    float cv[4][4], lo[4], hi[4], tau[4];
#pragma unroll
    for (int i = 0; i < 4; i++) {
      int row = wv * 4 + i;
      int c_ = cnt[row];
#pragma unroll
      for (int j = 0; j < 4; j++) {
        int p = lane + j * 64;
        cv[i][j] = (p < c_) ? candv[row][p] : -1e30f;
      }
      float mx = funkey(rowkey[row]);
      lo[i] = mx - 1.0f; hi[i] = mx;
    }
    for (int it = 0; it < 22; it++) {
      float mid[4], s[4];
#pragma unroll
      for (int i = 0; i < 4; i++) {
        mid[i] = 0.5f * (lo[i] + hi[i]);
        float ss = 0.0f;
#pragma unroll
        for (int j = 0; j < 4; j++) ss += fmaxf(cv[i][j] - mid[i], 0.0f);
        s[i] = ss;
      }
#pragma unroll
      for (int off = 32; off > 0; off >>= 1)
#pragma unroll
        for (int i = 0; i < 4; i++) s[i] += __shfl_xor(s[i], off, 64);
#pragma unroll
      for (int i = 0; i < 4; i++) {
        if (s[i] > 1.0f) lo[i] = mid[i]; else hi[i] = mid[i];
      }
    }
#pragma unroll
    for (int i = 0; i < 4; i++) tau[i] = 0.5f * (lo[i] + hi[i]);

    // ---- per row: compact true support (p>0), write global lists, PV ----
    float o[4];
#pragma unroll
    for (int i = 0; i < 4; i++) {
      int row = wv * 4 + i;
      size_t rowg = (size_t)blockIdx.x * 16 + row;
      int c_ = cnt[row];

      // read indices for my 4 slots BEFORE overwriting compacted positions
      unsigned short ki[4];
      float pv[4];
#pragma unroll
      for (int j = 0; j < 4; j++) {
        int p = lane + j * 64;
        ki[j] = candi[row][p];                  // p <= 255 < CAP, always in-bounds
        pv[j] = cv[i][j] - tau[i];
      }
      // ballot-prefix compaction (lockstep within wave -> no read/write hazard)
      int base = 0;
#pragma unroll
      for (int j = 0; j < 4; j++) {
        bool keep = (lane + j * 64 < c_) && (pv[j] > 0.0f);
        unsigned long long mk = __ballot(keep);
        if (keep) {
          int pos = base + __popcll(mk & lt_mask);
          candv[row][pos] = pv[j];
          candi[row][pos] = ki[j];
          candp_g[rowg * CAP + pos] = pv[j];
          candi_g[rowg * CAP + pos] = ki[j];
        }
        base += __popcll(mk);
      }
      if (lane == 0) cnt_g[rowg] = base;
      // zero-pad LDS list to multiple of 4 (pad entries: p=0, k=0 -> no-op in PV)
      if (lane < 3) {
        int pp = base + lane;
        if (pp < CAP) { candv[row][pp] = 0.0f; candi[row][pp] = 0; }
      }
      // 4-way unrolled PV over ~13 compacted entries (independent loads)
      float oa = 0.f, ob = 0.f, oc = 0.f, od = 0.f;
      for (int jj = 0; jj < base; jj += 4) {
        float p0 = candv[row][jj + 0]; int k0 = candi[row][jj + 0];
        float p1 = candv[row][jj + 1]; int k1 = candi[row][jj + 1];
        float p2 = candv[row][jj + 2]; int k2 = candi[row][jj + 2];
        float p3 = candv[row][jj + 3]; int k3 = candi[row][jj + 3];
        oa += p0 * bf2f(Vh[(size_t)k0 * Dv + lane]);
        ob += p1 * bf2f(Vh[(size_t)k1 * Dv + lane]);
        oc += p2 * bf2f(Vh[(size_t)k2 * Dv + lane]);
        od += p3 * bf2f(Vh[(size_t)k3 * Dv + lane]);
      }
      o[i] = (oa + ob) + (oc + od);
    }
#pragma unroll
    for (int i = 0; i < 4; i++) {
      int row = wv * 4 + i;
      Obf[((size_t)(b * Nv + qbase + row)) * Cv + h * Dv + lane] = f2bf(o[i]);
    }
  } else {
    // ---- pathological fallback: dense bisection via recompute; writes attn
    //      rows densely itself and flags cnt_g = -1 so attn_write skips ----
    if (threadIdx.x < 16) {
      float mx = funkey(rowkey[threadIdx.x]);
      lo_s[threadIdx.x] = mx - 1.0f; hi_s[threadIdx.x] = mx;
      cnt_g[(size_t)blockIdx.x * 16 + threadIdx.x] = -1;
    }
    __syncthreads();
    for (int it = 0; it < 26; it++) {
      if (threadIdx.x < 16) sum_s[threadIdx.x] = 0.0f;
      __syncthreads();
      float part[4] = {0, 0, 0, 0};
      for (int t = 0; t < 32; t++) {
        int col0 = (t * 4 + wv) * 16;
        s16x8 b0 = *(const s16x8*)(Kh + (size_t)(col0 + l16) * Dv + quad * 8);
        s16x8 b1 = *(const s16x8*)(Kh + (size_t)(col0 + l16) * Dv + 32 + quad * 8);
        f32x4 c = {};
        c = __builtin_amdgcn_mfma_f32_16x16x32_bf16(a0, b0, c, 0, 0, 0);
        c = __builtin_amdgcn_mfma_f32_16x16x32_bf16(a1, b1, c, 0, 0, 0);
#pragma unroll
        for (int r = 0; r < 4; r++) {
          int row = quad * 4 + r;
          float mid = 0.5f * (lo_s[row] + hi_s[row]);
          part[r] += fmaxf(c[r] * 0.125f - mid, 0.0f);
        }
      }
#pragma unroll
      for (int off = 1; off <= 8; off <<= 1)
#pragma unroll
        for (int r = 0; r < 4; r++) part[r] += __shfl_xor(part[r], off, 64);
      if (l16 == 0) {
#pragma unroll
        for (int r = 0; r < 4; r++) atomicAdd(&sum_s[quad * 4 + r], part[r]);
      }
      __syncthreads();
      if (threadIdx.x < 16) {
        float mid = 0.5f * (lo_s[threadIdx.x] + hi_s[threadIdx.x]);
        if (sum_s[threadIdx.x] > 1.0f) lo_s[threadIdx.x] = mid; else hi_s[threadIdx.x] = mid;
      }
      __syncthreads();
    }
    if (threadIdx.x < 16) taud[threadIdx.x] = 0.5f * (lo_s[threadIdx.x] + hi_s[threadIdx.x]);
    __syncthreads();
    // dense attn write by recompute
    for (int t = 0; t < 32; t++) {
      int col0 = (t * 4 + wv) * 16;
      s16x8 b0 = *(const s16x8*)(Kh + (size_t)(col0 + l16) * Dv + quad * 8);
      s16x8 b1 = *(const s16x8*)(Kh + (size_t)(col0 + l16) * Dv + 32 + quad * 8);
      f32x4 c = {};
      c = __builtin_amdgcn_mfma_f32_16x16x32_bf16(a0, b0, c, 0, 0, 0);
      c = __builtin_amdgcn_mfma_f32_16x16x32_bf16(a1, b1, c, 0, 0, 0);
#pragma unroll
      for (int r = 0; r < 4; r++) {
        int row = quad * 4 + r;
        attn_bh[(size_t)(qbase + row) * Nv + col0 + l16] =
            fmaxf(c[r] * 0.125f - taud[row], 0.0f);
      }
    }
    __threadfence();
    __syncthreads();
    // slow, correct PV: read back dense attn rows
    float o[4] = {0, 0, 0, 0};
#pragma unroll
    for (int i = 0; i < 4; i++) {
      int row = wv * 4 + i;
      const float* arow = attn_bh + (size_t)(qbase + row) * Nv;
      for (int k = 0; k < Nv; k++) {
        float p = arow[k];
        if (p > 0.0f) o[i] += p * bf2f(Vh[(size_t)k * Dv + lane]);
      }
    }
#pragma unroll
    for (int i = 0; i < 4; i++) {
      int row = wv * 4 + i;
      Obf[((size_t)(b * Nv + qbase + row)) * Cv + h * Dv + lane] = f2bf(o[i]);
    }
  }
}

// ---------------------------------------------------------------------------
// K2b: dense attn row writer. One 64-thread (single-wave) block per q-row:
// zero 8KB LDS row, scatter <=cnt entries, stream out as float4. Intra-wave
// barriers only -> no multi-wave barrier stalls. Skips fallback rows (cnt<0).
// ---------------------------------------------------------------------------
__global__ __launch_bounds__(64) void attn_write(
    const float* __restrict__ candp_g, const unsigned short* __restrict__ candi_g,
    const int* __restrict__ cnt_g, float* __restrict__ attn_out) {
  __shared__ float dense[Nv];
  const size_t rowg = blockIdx.x;
  const int t = threadIdx.x;
  const int c_ = cnt_g[rowg];
  if (c_ < 0) return;  // fallback row: already written densely

  float4* d4 = (float4*)dense;
  const float4 z4 = make_float4(0.f, 0.f, 0.f, 0.f);
#pragma unroll
  for (int j = 0; j < 8; j++) d4[j * 64 + t] = z4;
  __syncthreads();
  for (int jj = t; jj < c_; jj += 64)
    dense[candi_g[rowg * CAP + jj]] = candp_g[rowg * CAP + jj];
  __syncthreads();
  float* arow = attn_out + rowg * Nv;
#pragma unroll
  for (int j = 0; j < 8; j++)
    *(float4*)(arow + (j * 64 + t) * 4) = d4[j * 64 + t];
}

// ---------------------------------------------------------------------------
// K3: out = O @ Wo^T + bo (bf16 in, fp32 out)
// ---------------------------------------------------------------------------
__global__ __launch_bounds__(256) void proj_out(
    const unsigned short* __restrict__ Obf, const unsigned short* __restrict__ wob,
    const float* __restrict__ bo, float* __restrict__ out) {
  const int lane = threadIdx.x & 63;
  const int wv   = threadIdx.x >> 6;
  const int l16  = lane & 15, quad = lane >> 4;
  const int mbase = blockIdx.x * 64 + wv * 16;
  const int nbase = blockIdx.y * 64;

  f32x4 acc[4] = {};
  for (int kk = 0; kk < Cv; kk += 32) {
    s16x8 a = *(const s16x8*)(Obf + (size_t)(mbase + l16) * Cv + kk + quad * 8);
#pragma unroll
    for (int ct = 0; ct < 4; ct++) {
      s16x8 bfr = *(const s16x8*)(wob + (size_t)(nbase + ct * 16 + l16) * Cv + kk + quad * 8);
      acc[ct] = __builtin_amdgcn_mfma_f32_16x16x32_bf16(a, bfr, acc[ct], 0, 0, 0);
    }
  }
#pragma unroll
  for (int ct = 0; ct < 4; ct++) {
    int n = nbase + ct * 16 + l16;
    float bb = bo[n];
#pragma unroll
    for (int r = 0; r < 4; r++) {
      int m = mbase + quad * 4 + r;
      out[(size_t)m * Cv + n] = acc[ct][r] + bb;
    }
  }
}

extern "C" void kernel_launch(void* const* d_in, const int* in_sizes, int n_in,
                              void* d_out, int out_size, void* d_ws, size_t ws_size,
                              hipStream_t stream) {
  (void)in_sizes; (void)n_in; (void)out_size; (void)ws_size;
  const float* x  = (const float*)d_in[0];
  const float* Wq = (const float*)d_in[1];
  const float* bq = (const float*)d_in[2];
  const float* Wk = (const float*)d_in[3];
  const float* bk = (const float*)d_in[4];
  const float* Wv = (const float*)d_in[5];
  const float* bv = (const float*)d_in[6];
  const float* Wo = (const float*)d_in[7];
  const float* bo = (const float*)d_in[8];

  float* out  = (float*)d_out;                       // [B,N,C]
  float* attn = out + (size_t)Bv * Nv * Cv;          // [B,H,N,N]

  const size_t NROWS = (size_t)Bv * Hv * Nv;         // 32768

  unsigned short* xb  = (unsigned short*)d_ws;
  unsigned short* wqb = xb  + (size_t)Bv * Nv * Cv;
  unsigned short* wkb = wqb + (size_t)Cv * Cv;
  unsigned short* wvb = wkb + (size_t)Cv * Cv;
  unsigned short* wob = wvb + (size_t)Cv * Cv;
  unsigned short* Qbf = wob + (size_t)Cv * Cv;
  unsigned short* Kbf = Qbf + (size_t)Bv * Hv * Nv * Dv;
  unsigned short* Vbf = Kbf + (size_t)Bv * Hv * Nv * Dv;
  unsigned short* end16 = Vbf + (size_t)Bv * Hv * Nv * Dv;
  float*          candp = (float*)end16;             // 32768*CAP f32 = 33.5MB
  unsigned short* candi = (unsigned short*)(candp + NROWS * CAP);  // 16.8MB
  int*            cntg  = (int*)(candi + NROWS * CAP);             // 128KB
  unsigned short* Obf = xb;   // alias: xb dead after proj_qkv

  cvt5<<<dim3((Bv * Nv * Cv) / 4 / 256, 5), 256, 0, stream>>>(
      x, Wq, Wk, Wv, Wo, xb, wqb, wkb, wvb, wob);
  proj_qkv<<<dim3((Bv * Nv) / 64, Cv / 64, 3), 256, 0, stream>>>(
      xb, wqb, bq, wkb, bk, wvb, bv, Qbf, Kbf, Vbf);
  attn_sparse<<<dim3(Bv * Hv * (Nv / 16)), 256, 0, stream>>>(
      Qbf, Kbf, Vbf, attn, Obf, candp, candi, cntg);
  attn_write<<<dim3((unsigned)NROWS), 64, 0, stream>>>(candp, candi, cntg, attn);
  proj_out<<<dim3((Bv * Nv) / 64, Cv / 64), 256, 0, stream>>>(Obf, wob, bo, out);
}